// Round 1
// baseline (720.397 us; speedup 1.0000x reference)
//
#include <hip/hip_runtime.h>
#include <hip/hip_bf16.h>

#define NN 8192
#define MM 128
#define EPSF 1e-4f
#define SHIFT 30.0f

typedef __bf16 bf16x8 __attribute__((ext_vector_type(8)));
typedef __bf16 bf16x4 __attribute__((ext_vector_type(4)));
typedef float floatx4 __attribute__((ext_vector_type(4)));

// fp32 -> bf16 conversion of out1 & out2 (blockIdx.y selects tensor)
__global__ void convert_kernel(const float* __restrict__ in0,
                               const float* __restrict__ in1,
                               __bf16* __restrict__ o0,
                               __bf16* __restrict__ o1) {
    const float* in = blockIdx.y ? in1 : in0;
    __bf16* out = blockIdx.y ? o1 : o0;
    int i = (blockIdx.x * blockDim.x + threadIdx.x) * 4;
    float4 v = *reinterpret_cast<const float4*>(in + i);
    bf16x4 o = { (__bf16)v.x, (__bf16)v.y, (__bf16)v.z, (__bf16)v.w };
    *reinterpret_cast<bf16x4*>(out + i) = o;
}

// lsum[i] += sum_j exp( dot(A[i,:],B[j,:]) - SHIFT ),  i in [0,NN), j over a 2048 chunk
__global__ __launch_bounds__(256)
void rowsum_kernel(const __bf16* __restrict__ A, const __bf16* __restrict__ B,
                   float* __restrict__ lsum) {
    const int wave = threadIdx.x >> 6;
    const int lane = threadIdx.x & 63;
    const int q = lane >> 4;       // quad 0..3
    const int ln = lane & 15;
    const int row0 = blockIdx.x * 64 + wave * 16;
    const int jbase = blockIdx.y * 2048;

    const __bf16* arow = A + (size_t)(row0 + ln) * MM + q * 8;
    bf16x8 a0 = *reinterpret_cast<const bf16x8*>(arow + 0);
    bf16x8 a1 = *reinterpret_cast<const bf16x8*>(arow + 32);
    bf16x8 a2 = *reinterpret_cast<const bf16x8*>(arow + 64);
    bf16x8 a3 = *reinterpret_cast<const bf16x8*>(arow + 96);

    float p0 = 0.f, p1 = 0.f, p2 = 0.f, p3 = 0.f;
    for (int j0 = jbase; j0 < jbase + 2048; j0 += 16) {
        const __bf16* brow = B + (size_t)(j0 + ln) * MM + q * 8;
        bf16x8 b0 = *reinterpret_cast<const bf16x8*>(brow + 0);
        bf16x8 b1 = *reinterpret_cast<const bf16x8*>(brow + 32);
        bf16x8 b2 = *reinterpret_cast<const bf16x8*>(brow + 64);
        bf16x8 b3 = *reinterpret_cast<const bf16x8*>(brow + 96);
        floatx4 acc = {0.f, 0.f, 0.f, 0.f};
        acc = __builtin_amdgcn_mfma_f32_16x16x32_bf16(a0, b0, acc, 0, 0, 0);
        acc = __builtin_amdgcn_mfma_f32_16x16x32_bf16(a1, b1, acc, 0, 0, 0);
        acc = __builtin_amdgcn_mfma_f32_16x16x32_bf16(a2, b2, acc, 0, 0, 0);
        acc = __builtin_amdgcn_mfma_f32_16x16x32_bf16(a3, b3, acc, 0, 0, 0);
        p0 += __expf(acc[0] - SHIFT);
        p1 += __expf(acc[1] - SHIFT);
        p2 += __expf(acc[2] - SHIFT);
        p3 += __expf(acc[3] - SHIFT);
    }
    // reduce across the 16 lanes of each quad (cols) -> row sums
    #pragma unroll
    for (int m = 1; m <= 8; m <<= 1) {
        p0 += __shfl_xor(p0, m);
        p1 += __shfl_xor(p1, m);
        p2 += __shfl_xor(p2, m);
        p3 += __shfl_xor(p3, m);
    }
    if (ln == 0) {
        atomicAdd(&lsum[row0 + q * 4 + 0], p0);
        atomicAdd(&lsum[row0 + q * 4 + 1], p1);
        atomicAdd(&lsum[row0 + q * 4 + 2], p2);
        atomicAdd(&lsum[row0 + q * 4 + 3], p3);
    }
}

// loss = sum_ij -label[i,j] * ( log(e*rl_i + eps) + log(e*rc_j + eps) ),  e = exp(s-SHIFT)
__global__ __launch_bounds__(256)
void loss_kernel(const __bf16* __restrict__ A, const __bf16* __restrict__ B,
                 const float* __restrict__ lrow, const float* __restrict__ lcol,
                 const float* __restrict__ label, float* __restrict__ out) {
    const int wave = threadIdx.x >> 6;
    const int lane = threadIdx.x & 63;
    const int q = lane >> 4;
    const int ln = lane & 15;
    const int i0 = blockIdx.y * 64 + wave * 16;  // rows of S
    const int j0 = blockIdx.x * 64;              // cols of S

    const __bf16* arow = A + (size_t)(i0 + ln) * MM + q * 8;
    bf16x8 a0 = *reinterpret_cast<const bf16x8*>(arow + 0);
    bf16x8 a1 = *reinterpret_cast<const bf16x8*>(arow + 32);
    bf16x8 a2 = *reinterpret_cast<const bf16x8*>(arow + 64);
    bf16x8 a3 = *reinterpret_cast<const bf16x8*>(arow + 96);

    float rlr[4];
    #pragma unroll
    for (int r = 0; r < 4; r++) rlr[r] = 1.0f / lrow[i0 + q * 4 + r];

    float lacc = 0.f;
    #pragma unroll
    for (int cg = 0; cg < 4; cg++) {
        const int j = j0 + cg * 16;
        const __bf16* brow = B + (size_t)(j + ln) * MM + q * 8;
        bf16x8 b0 = *reinterpret_cast<const bf16x8*>(brow + 0);
        bf16x8 b1 = *reinterpret_cast<const bf16x8*>(brow + 32);
        bf16x8 b2 = *reinterpret_cast<const bf16x8*>(brow + 64);
        bf16x8 b3 = *reinterpret_cast<const bf16x8*>(brow + 96);
        floatx4 acc = {0.f, 0.f, 0.f, 0.f};
        acc = __builtin_amdgcn_mfma_f32_16x16x32_bf16(a0, b0, acc, 0, 0, 0);
        acc = __builtin_amdgcn_mfma_f32_16x16x32_bf16(a1, b1, acc, 0, 0, 0);
        acc = __builtin_amdgcn_mfma_f32_16x16x32_bf16(a2, b2, acc, 0, 0, 0);
        acc = __builtin_amdgcn_mfma_f32_16x16x32_bf16(a3, b3, acc, 0, 0, 0);

        float rc = 1.0f / lcol[j + ln];
        #pragma unroll
        for (int r = 0; r < 4; r++) {
            float e = __expf(acc[r] - SHIFT);
            float t = __logf(fmaf(e, rlr[r], EPSF)) + __logf(fmaf(e, rc, EPSF));
            float lb = label[(size_t)(i0 + q * 4 + r) * NN + j + ln];
            lacc = fmaf(-lb, t, lacc);
        }
    }
    // full-wave reduce
    #pragma unroll
    for (int m = 1; m <= 32; m <<= 1) lacc += __shfl_xor(lacc, m);
    __shared__ float red[4];
    if (lane == 0) red[wave] = lacc;
    __syncthreads();
    if (threadIdx.x == 0)
        atomicAdd(out, red[0] + red[1] + red[2] + red[3]);
}

extern "C" void kernel_launch(void* const* d_in, const int* in_sizes, int n_in,
                              void* d_out, int out_size, void* d_ws, size_t ws_size,
                              hipStream_t stream) {
    const float* out1 = (const float*)d_in[0];
    const float* out2 = (const float*)d_in[1];
    const float* label = (const float*)d_in[2];
    float* out = (float*)d_out;

    char* ws = (char*)d_ws;
    __bf16* out1b = (__bf16*)ws;                       // 2 MB
    __bf16* out2b = (__bf16*)(ws + (size_t)2097152);   // 2 MB
    float* l_row = (float*)(ws + (size_t)4194304);     // 32 KB
    float* l_col = l_row + NN;                         // 32 KB

    hipMemsetAsync(l_row, 0, 2 * NN * sizeof(float), stream);
    hipMemsetAsync(d_out, 0, sizeof(float), stream);

    convert_kernel<<<dim3(1024, 2), 256, 0, stream>>>(out1, out2, out1b, out2b);

    // l_row[i] = sum_j exp(S[i,j]-SHIFT), S = out2 @ out1^T
    rowsum_kernel<<<dim3(NN / 64, 4), 256, 0, stream>>>(out2b, out1b, l_row);
    // l_col[j] = sum_i exp(S[i,j]-SHIFT)  (= row sums of out1 @ out2^T)
    rowsum_kernel<<<dim3(NN / 64, 4), 256, 0, stream>>>(out1b, out2b, l_col);

    loss_kernel<<<dim3(NN / 64, NN / 64), 256, 0, stream>>>(out2b, out1b, l_row, l_col,
                                                            label, out);
}

// Round 2
// 547.995 us; speedup vs baseline: 1.3146x; 1.3146x over previous
//
#include <hip/hip_runtime.h>
#include <hip/hip_bf16.h>

#define NN 8192
#define MM 128
#define EPSF 1e-4f
#define SHIFT 30.0f
#define BC 1024          // cols per block
#define NJ (BC / 64)     // 16 jsteps of 64 cols
#define NCB (NN / BC)    // 8 col chunks
#define NRB (NN / 64)    // 128 row blocks
#define LSTR 68          // LDS label row stride (floats): 2-way bank access = free

typedef __bf16 bf16x8 __attribute__((ext_vector_type(8)));
typedef __bf16 bf16x4 __attribute__((ext_vector_type(4)));
typedef float floatx4 __attribute__((ext_vector_type(4)));

// fp32 -> bf16 conversion of out1 & out2 (blockIdx.y selects tensor)
__global__ void convert_kernel(const float* __restrict__ in0,
                               const float* __restrict__ in1,
                               __bf16* __restrict__ o0,
                               __bf16* __restrict__ o1) {
    const float* in = blockIdx.y ? in1 : in0;
    __bf16* out = blockIdx.y ? o1 : o0;
    int i = (blockIdx.x * blockDim.x + threadIdx.x) * 4;
    float4 v = *reinterpret_cast<const float4*>(in + i);
    bf16x4 o = { (__bf16)v.x, (__bf16)v.y, (__bf16)v.z, (__bf16)v.w };
    *reinterpret_cast<bf16x4*>(out + i) = o;
}

// One pass over S = A @ B^T (A=out2b, B=out1b): accumulate row-sum partials
// (registers -> slice per col-chunk) and col-sum partials (LDS -> slice per
// row-block) of exp(S - SHIFT). Atomic-free: partial slices reduced later.
__global__ __launch_bounds__(256)
void sums_kernel(const __bf16* __restrict__ A, const __bf16* __restrict__ B,
                 float* __restrict__ rowp,   // [NCB][NN]
                 float* __restrict__ colp) { // [NRB][NN]
    __shared__ float colacc[4][BC];
    const int tid = threadIdx.x;
    const int w = tid >> 6, lane = tid & 63, q = lane >> 4, ln = lane & 15;
    const int i0 = blockIdx.y * 64 + w * 16;
    const int jbase = blockIdx.x * BC;

    for (int k = tid; k < 4 * BC; k += 256) ((float*)colacc)[k] = 0.f;
    __syncthreads();

    const __bf16* arow = A + (size_t)(i0 + ln) * MM + q * 8;
    bf16x8 a0 = *reinterpret_cast<const bf16x8*>(arow + 0);
    bf16x8 a1 = *reinterpret_cast<const bf16x8*>(arow + 32);
    bf16x8 a2 = *reinterpret_cast<const bf16x8*>(arow + 64);
    bf16x8 a3 = *reinterpret_cast<const bf16x8*>(arow + 96);

    float p[4] = {0.f, 0.f, 0.f, 0.f};

    for (int js = 0; js < NJ; ++js) {
        const int j0 = jbase + js * 64;
        bf16x8 b[4][4];
        #pragma unroll
        for (int cg = 0; cg < 4; ++cg) {
            const __bf16* br = B + (size_t)(j0 + cg * 16 + ln) * MM + q * 8;
            b[cg][0] = *reinterpret_cast<const bf16x8*>(br + 0);
            b[cg][1] = *reinterpret_cast<const bf16x8*>(br + 32);
            b[cg][2] = *reinterpret_cast<const bf16x8*>(br + 64);
            b[cg][3] = *reinterpret_cast<const bf16x8*>(br + 96);
        }
        #pragma unroll
        for (int cg = 0; cg < 4; ++cg) {
            floatx4 acc = {0.f, 0.f, 0.f, 0.f};
            acc = __builtin_amdgcn_mfma_f32_16x16x32_bf16(a0, b[cg][0], acc, 0, 0, 0);
            acc = __builtin_amdgcn_mfma_f32_16x16x32_bf16(a1, b[cg][1], acc, 0, 0, 0);
            acc = __builtin_amdgcn_mfma_f32_16x16x32_bf16(a2, b[cg][2], acc, 0, 0, 0);
            acc = __builtin_amdgcn_mfma_f32_16x16x32_bf16(a3, b[cg][3], acc, 0, 0, 0);
            float e0 = __expf(acc[0] - SHIFT);
            float e1 = __expf(acc[1] - SHIFT);
            float e2 = __expf(acc[2] - SHIFT);
            float e3 = __expf(acc[3] - SHIFT);
            p[0] += e0; p[1] += e1; p[2] += e2; p[3] += e3;
            float c = (e0 + e1) + (e2 + e3);
            c += __shfl_xor(c, 16);
            c += __shfl_xor(c, 32);
            if (q == 0) colacc[w][js * 64 + cg * 16 + ln] += c;
        }
    }

    // row-sum reduce across the 16 ln lanes of each quad
    #pragma unroll
    for (int m = 1; m <= 8; m <<= 1) {
        p[0] += __shfl_xor(p[0], m);
        p[1] += __shfl_xor(p[1], m);
        p[2] += __shfl_xor(p[2], m);
        p[3] += __shfl_xor(p[3], m);
    }
    if (ln == 0) {
        float4 v = {p[0], p[1], p[2], p[3]};
        *reinterpret_cast<float4*>(&rowp[(size_t)blockIdx.x * NN + i0 + q * 4]) = v;
    }
    __syncthreads();
    for (int k = tid; k < BC; k += 256) {
        colp[(size_t)blockIdx.y * NN + jbase + k] =
            (colacc[0][k] + colacc[1][k]) + (colacc[2][k] + colacc[3][k]);
    }
}

// lrow[i] = sum of NCB rowp slices; lcol[i] = sum of NRB colp slices
__global__ __launch_bounds__(256)
void reduce_kernel(const float* __restrict__ rowp, const float* __restrict__ colp,
                   float* __restrict__ lrow, float* __restrict__ lcol) {
    int i = blockIdx.x * 256 + threadIdx.x;
    float r = 0.f;
    #pragma unroll
    for (int k = 0; k < NCB; ++k) r += rowp[(size_t)k * NN + i];
    lrow[i] = r;
    float c = 0.f;
    #pragma unroll 16
    for (int k = 0; k < NRB; ++k) c += colp[(size_t)k * NN + i];
    lcol[i] = c;
}

// loss = sum_ij -label[i,j] * ( log(e*rl_i + eps) + log(e*rc_j + eps) )
// label staged through double-buffered LDS with cooperative float4 loads.
__global__ __launch_bounds__(256)
void loss_kernel(const __bf16* __restrict__ A, const __bf16* __restrict__ B,
                 const float* __restrict__ lrow, const float* __restrict__ lcol,
                 const float* __restrict__ label, float* __restrict__ out) {
    __shared__ float lab[2][64 * LSTR];
    __shared__ float red[4];
    const int tid = threadIdx.x;
    const int w = tid >> 6, lane = tid & 63, q = lane >> 4, ln = lane & 15;
    const int i0 = blockIdx.y * 64 + w * 16;
    const int jbase = blockIdx.x * BC;

    const __bf16* arow = A + (size_t)(i0 + ln) * MM + q * 8;
    bf16x8 a0 = *reinterpret_cast<const bf16x8*>(arow + 0);
    bf16x8 a1 = *reinterpret_cast<const bf16x8*>(arow + 32);
    bf16x8 a2 = *reinterpret_cast<const bf16x8*>(arow + 64);
    bf16x8 a3 = *reinterpret_cast<const bf16x8*>(arow + 96);

    float rlr[4];
    #pragma unroll
    for (int r = 0; r < 4; ++r) rlr[r] = 1.0f / lrow[i0 + q * 4 + r];

    // staging geometry: thread loads rows srow+{0,16,32,48}, 4 consecutive cols
    const int srow = tid >> 4;          // 0..15
    const int scol = (tid & 15) * 4;    // 0,4,..,60
    const float* sbase = label + (size_t)(blockIdx.y * 64 + srow) * NN + jbase + scol;
    float4 s0, s1, s2, s3;

    #define STAGE_LOAD(js)                                                     \
        do {                                                                   \
            const float* p_ = sbase + (js) * 64;                               \
            s0 = *reinterpret_cast<const float4*>(p_);                         \
            s1 = *reinterpret_cast<const float4*>(p_ + (size_t)16 * NN);       \
            s2 = *reinterpret_cast<const float4*>(p_ + (size_t)32 * NN);       \
            s3 = *reinterpret_cast<const float4*>(p_ + (size_t)48 * NN);       \
        } while (0)
    #define STAGE_WRITE(b)                                                     \
        do {                                                                   \
            float* p_ = &lab[b][srow * LSTR + scol];                           \
            *reinterpret_cast<float4*>(p_) = s0;                               \
            *reinterpret_cast<float4*>(p_ + 16 * LSTR) = s1;                   \
            *reinterpret_cast<float4*>(p_ + 32 * LSTR) = s2;                   \
            *reinterpret_cast<float4*>(p_ + 48 * LSTR) = s3;                   \
        } while (0)

    STAGE_LOAD(0);
    STAGE_WRITE(0);
    int buf = 0;

    float lacc = 0.f;
    for (int js = 0; js < NJ; ++js) {
        __syncthreads();
        if (js + 1 < NJ) STAGE_LOAD(js + 1);
        const int j0 = jbase + js * 64;
        const float* L = &lab[buf][(w * 16 + q * 4) * LSTR];
        #pragma unroll
        for (int cg = 0; cg < 4; ++cg) {
            const __bf16* br = B + (size_t)(j0 + cg * 16 + ln) * MM + q * 8;
            bf16x8 b0 = *reinterpret_cast<const bf16x8*>(br + 0);
            bf16x8 b1 = *reinterpret_cast<const bf16x8*>(br + 32);
            bf16x8 b2 = *reinterpret_cast<const bf16x8*>(br + 64);
            bf16x8 b3 = *reinterpret_cast<const bf16x8*>(br + 96);
            float rc = 1.0f / lcol[j0 + cg * 16 + ln];
            floatx4 acc = {0.f, 0.f, 0.f, 0.f};
            acc = __builtin_amdgcn_mfma_f32_16x16x32_bf16(a0, b0, acc, 0, 0, 0);
            acc = __builtin_amdgcn_mfma_f32_16x16x32_bf16(a1, b1, acc, 0, 0, 0);
            acc = __builtin_amdgcn_mfma_f32_16x16x32_bf16(a2, b2, acc, 0, 0, 0);
            acc = __builtin_amdgcn_mfma_f32_16x16x32_bf16(a3, b3, acc, 0, 0, 0);
            #pragma unroll
            for (int r = 0; r < 4; ++r) {
                float e = __expf(acc[r] - SHIFT);
                float t = __logf(fmaf(e, rlr[r], EPSF)) + __logf(fmaf(e, rc, EPSF));
                float lb = L[r * LSTR + cg * 16 + ln];
                lacc = fmaf(lb, t, lacc);
            }
        }
        if (js + 1 < NJ) STAGE_WRITE(buf ^ 1);
        buf ^= 1;
    }

    #pragma unroll
    for (int m = 1; m <= 32; m <<= 1) lacc += __shfl_xor(lacc, m);
    if (lane == 0) red[w] = lacc;
    __syncthreads();
    if (tid == 0) atomicAdd(out, -((red[0] + red[1]) + (red[2] + red[3])));
}

extern "C" void kernel_launch(void* const* d_in, const int* in_sizes, int n_in,
                              void* d_out, int out_size, void* d_ws, size_t ws_size,
                              hipStream_t stream) {
    const float* out1 = (const float*)d_in[0];
    const float* out2 = (const float*)d_in[1];
    const float* label = (const float*)d_in[2];

    char* ws = (char*)d_ws;
    __bf16* out1b = (__bf16*)ws;                            // 2 MB
    __bf16* out2b = (__bf16*)(ws + (size_t)(2 << 20));      // 2 MB
    float* rowp  = (float*)(ws + (size_t)(4 << 20));        // NCB*NN*4 = 256 KB
    float* colp  = (float*)(ws + (size_t)(4 << 20) + 262144);   // NRB*NN*4 = 4 MB
    float* lrow  = (float*)(ws + (size_t)(9 << 20));        // 32 KB
    float* lcol  = lrow + NN;                               // 32 KB

    hipMemsetAsync(d_out, 0, sizeof(float), stream);

    convert_kernel<<<dim3(1024, 2), 256, 0, stream>>>(out1, out2, out1b, out2b);

    // S = out2b @ out1b^T; rowp/colp are atomic-free partial slices
    sums_kernel<<<dim3(NCB, NRB), 256, 0, stream>>>(out2b, out1b, rowp, colp);
    reduce_kernel<<<dim3(NN / 256), 256, 0, stream>>>(rowp, colp, lrow, lcol);

    loss_kernel<<<dim3(NCB, NRB), 256, 0, stream>>>(out2b, out1b, lrow, lcol,
                                                    label, (float*)d_out);
}

// Round 3
// 509.575 us; speedup vs baseline: 1.4137x; 1.0754x over previous
//
#include <hip/hip_runtime.h>
#include <hip/hip_bf16.h>

#define NN 8192
#define MM 128
#define EPSF 1e-4f
#define SHIFT 30.0f

typedef __bf16 bf16x8 __attribute__((ext_vector_type(8)));
typedef __bf16 bf16x4 __attribute__((ext_vector_type(4)));
typedef float floatx4 __attribute__((ext_vector_type(4)));

// fp32 -> bf16 conversion of out1 & out2 (blockIdx.y selects tensor)
__global__ void convert_kernel(const float* __restrict__ in0,
                               const float* __restrict__ in1,
                               __bf16* __restrict__ o0,
                               __bf16* __restrict__ o1) {
    const float* in = blockIdx.y ? in1 : in0;
    __bf16* out = blockIdx.y ? o1 : o0;
    int i = (blockIdx.x * blockDim.x + threadIdx.x) * 4;
    float4 v = *reinterpret_cast<const float4*>(in + i);
    bf16x4 o = { (__bf16)v.x, (__bf16)v.y, (__bf16)v.z, (__bf16)v.w };
    *reinterpret_cast<bf16x4*>(out + i) = o;
}

#define LOAD_A(dst, ptr)                                                   \
    do {                                                                   \
        dst[0] = *reinterpret_cast<const bf16x8*>((ptr) + 0);              \
        dst[1] = *reinterpret_cast<const bf16x8*>((ptr) + 32);             \
        dst[2] = *reinterpret_cast<const bf16x8*>((ptr) + 64);             \
        dst[3] = *reinterpret_cast<const bf16x8*>((ptr) + 96);             \
    } while (0)

// sums[0][i] = sum_j exp(S[i,j]-SHIFT) with S = out2 @ out1^T (dir 0)
// sums[1][j] = sum_i exp(S[i,j]-SHIFT)  (= row sums of out1 @ out2^T, dir 1)
// No LDS, no barriers: register accumulation, 4 shuffles at the end, atomics.
__global__ __launch_bounds__(256)
void rowsum_kernel(const __bf16* __restrict__ X2, const __bf16* __restrict__ X1,
                   float* __restrict__ sums) {
    const int dir = blockIdx.z;
    const __bf16* A = dir ? X1 : X2;
    const __bf16* B = dir ? X2 : X1;
    float* sum = sums + dir * NN;

    const int tid = threadIdx.x;
    const int w = tid >> 6, lane = tid & 63, q = lane >> 4, ln = lane & 15;
    const int i0 = blockIdx.y * 128 + w * 32;   // 32 rows per wave (2 row-groups)
    const int jbase = blockIdx.x * 1024;

    bf16x8 a[2][4];
    #pragma unroll
    for (int rg = 0; rg < 2; ++rg) {
        const __bf16* ar = A + (size_t)(i0 + rg * 16 + ln) * MM + q * 8;
        LOAD_A(a[rg], ar);
    }

    float p[2][4] = {{0.f, 0.f, 0.f, 0.f}, {0.f, 0.f, 0.f, 0.f}};

    for (int js = 0; js < 16; ++js) {
        const int j0 = jbase + js * 64;
        #pragma unroll
        for (int cg = 0; cg < 4; ++cg) {
            const __bf16* br = B + (size_t)(j0 + cg * 16 + ln) * MM + q * 8;
            bf16x8 b[4];
            LOAD_A(b, br);
            floatx4 acc0 = {0.f, 0.f, 0.f, 0.f};
            floatx4 acc1 = {0.f, 0.f, 0.f, 0.f};
            #pragma unroll
            for (int k = 0; k < 4; ++k) {
                acc0 = __builtin_amdgcn_mfma_f32_16x16x32_bf16(a[0][k], b[k], acc0, 0, 0, 0);
                acc1 = __builtin_amdgcn_mfma_f32_16x16x32_bf16(a[1][k], b[k], acc1, 0, 0, 0);
            }
            #pragma unroll
            for (int r = 0; r < 4; ++r) {
                p[0][r] += __expf(acc0[r] - SHIFT);
                p[1][r] += __expf(acc1[r] - SHIFT);
            }
        }
    }

    // reduce across the 16 ln-lanes of each quad (rows live on (q,r))
    #pragma unroll
    for (int m = 1; m <= 8; m <<= 1) {
        #pragma unroll
        for (int rg = 0; rg < 2; ++rg)
            #pragma unroll
            for (int r = 0; r < 4; ++r)
                p[rg][r] += __shfl_xor(p[rg][r], m);
    }
    if (ln == 0) {
        #pragma unroll
        for (int rg = 0; rg < 2; ++rg)
            #pragma unroll
            for (int r = 0; r < 4; ++r)
                atomicAdd(&sum[i0 + rg * 16 + q * 4 + r], p[rg][r]);
    }
}

__global__ void recip_kernel(const float* __restrict__ s, float* __restrict__ r) {
    int i = blockIdx.x * 256 + threadIdx.x;
    r[i] = 1.0f / s[i];
}

// loss = sum_ij -label[i,j] * log( (e*rl_i+eps)*(e*rc_j+eps) ),  e = exp(s-SHIFT)
// No LDS staging: label loaded directly in MFMA C-layout (dword, 4x64B segments).
__global__ __launch_bounds__(256)
void loss_kernel(const __bf16* __restrict__ A, const __bf16* __restrict__ B,
                 const float* __restrict__ lrowR, const float* __restrict__ lcolR,
                 const float* __restrict__ label, float* __restrict__ out) {
    const int tid = threadIdx.x;
    const int w = tid >> 6, lane = tid & 63, q = lane >> 4, ln = lane & 15;
    const int i0 = blockIdx.y * 128 + w * 32;   // 32 rows per wave
    const int jbase = blockIdx.x * 256;         // 256 cols per block

    bf16x8 a[2][4];
    float rlr[2][4];
    const float* labrow[2][4];
    #pragma unroll
    for (int rg = 0; rg < 2; ++rg) {
        const __bf16* ar = A + (size_t)(i0 + rg * 16 + ln) * MM + q * 8;
        LOAD_A(a[rg], ar);
        #pragma unroll
        for (int r = 0; r < 4; ++r) {
            const int row = i0 + rg * 16 + q * 4 + r;
            rlr[rg][r] = lrowR[row];
            labrow[rg][r] = label + (size_t)row * NN;
        }
    }

    float lacc = 0.f;
    for (int js = 0; js < 4; ++js) {
        const int j0 = jbase + js * 64;
        #pragma unroll
        for (int cg = 0; cg < 4; ++cg) {
            const int col = j0 + cg * 16 + ln;
            const __bf16* br = B + (size_t)col * MM + q * 8;
            bf16x8 b[4];
            LOAD_A(b, br);
            float rc = lcolR[col];
            float lb[2][4];
            #pragma unroll
            for (int rg = 0; rg < 2; ++rg)
                #pragma unroll
                for (int r = 0; r < 4; ++r) lb[rg][r] = labrow[rg][r][col];

            floatx4 acc0 = {0.f, 0.f, 0.f, 0.f};
            floatx4 acc1 = {0.f, 0.f, 0.f, 0.f};
            #pragma unroll
            for (int k = 0; k < 4; ++k) {
                acc0 = __builtin_amdgcn_mfma_f32_16x16x32_bf16(a[0][k], b[k], acc0, 0, 0, 0);
                acc1 = __builtin_amdgcn_mfma_f32_16x16x32_bf16(a[1][k], b[k], acc1, 0, 0, 0);
            }
            #pragma unroll
            for (int r = 0; r < 4; ++r) {
                float e0 = __expf(acc0[r] - SHIFT);
                float t0 = __logf(fmaf(e0, rlr[0][r], EPSF) * fmaf(e0, rc, EPSF));
                lacc = fmaf(lb[0][r], t0, lacc);
                float e1 = __expf(acc1[r] - SHIFT);
                float t1 = __logf(fmaf(e1, rlr[1][r], EPSF) * fmaf(e1, rc, EPSF));
                lacc = fmaf(lb[1][r], t1, lacc);
            }
        }
    }

    #pragma unroll
    for (int m = 1; m <= 32; m <<= 1) lacc += __shfl_xor(lacc, m);
    __shared__ float red[4];
    if (lane == 0) red[w] = lacc;
    __syncthreads();
    if (tid == 0) atomicAdd(out, -((red[0] + red[1]) + (red[2] + red[3])));
}

extern "C" void kernel_launch(void* const* d_in, const int* in_sizes, int n_in,
                              void* d_out, int out_size, void* d_ws, size_t ws_size,
                              hipStream_t stream) {
    const float* out1 = (const float*)d_in[0];
    const float* out2 = (const float*)d_in[1];
    const float* label = (const float*)d_in[2];

    char* ws = (char*)d_ws;
    __bf16* out1b = (__bf16*)ws;                          // 2 MB
    __bf16* out2b = (__bf16*)(ws + (size_t)(2 << 20));    // 2 MB
    float* sums   = (float*)(ws + (size_t)(4 << 20));     // 2*NN floats (64 KB)
    float* recips = sums + 2 * NN;                        // 2*NN floats (64 KB)

    hipMemsetAsync(sums, 0, 2 * NN * sizeof(float), stream);
    hipMemsetAsync(d_out, 0, sizeof(float), stream);

    convert_kernel<<<dim3(1024, 2), 256, 0, stream>>>(out1, out2, out1b, out2b);

    // both directions in one dispatch: z=0 row sums, z=1 col sums
    rowsum_kernel<<<dim3(8, 64, 2), 256, 0, stream>>>(out2b, out1b, sums);
    recip_kernel<<<dim3(64), 256, 0, stream>>>(sums, recips);

    loss_kernel<<<dim3(32, 64), 256, 0, stream>>>(out2b, out1b,
                                                  recips,          // 1/rowsum
                                                  recips + NN,     // 1/colsum
                                                  label, (float*)d_out);
}